// Round 10
// baseline (50.658 us; speedup 1.0000x reference)
//
#include <hip/hip_runtime.h>
#include <math.h>

#define N_SURF 40000
#define N_LIG  1024
#define HID    512
#define E_MAX  131072
#define L5     5

// workspace float layout
#define WS_WP     0        // 512*3  : Wp = W_gcn[5] @ W_pos
#define WS_A3     1536     // 9      : W_surf @ Wp
#define WS_BSP    1545     // 3      : b_surf @ Wp
#define WS_BPOUT  1548     // 3      : b_gcn[5]@W_pos + b_pos
#define WS_WHBP   1552     // 64*3   : W_hbias @ Wp
#define WS_AGG    1744     // 1024*3 : sum of surface_pos over in-edges
#define WS_CNT    4816     // 1024   : in-degree
#define WS_ZERO_BEGIN 1744
#define WS_ZERO_COUNT 4096 // AGG + CNT

// ---- K1 (581 blocks):
//   b in [0,512):   edge scatter (256 edges each); b<128 also Wp rows 4b..4b+3
//   b in [512,576): Whbp row (b-512)  = (Whb[r,:]@Wgcn5)@Wpos   [direct, no Wp dep]
//   b in [576,579): A3 row (b-576)    = (Wsurf[a,:]@Wgcn5)@Wpos
//   b == 579:       bsp               = (bsurf@Wgcn5)@Wpos
//   b == 580:       bpout             = bgcn[5]@Wpos + bpos
__global__ __launch_bounds__(256) void k1(
    const float* __restrict__ Wgcn,  const float* __restrict__ Wpos,
    const float* __restrict__ Wsurf, const float* __restrict__ bsurf,
    const float* __restrict__ bgcn,  const float* __restrict__ bpos,
    const float* __restrict__ Whb,
    const int*   __restrict__ ei,    const float* __restrict__ spos,
    float* __restrict__ ws)
{
    int t    = threadIdx.x;
    int lane = t & 63;
    int w    = t >> 6;
    int b    = blockIdx.x;
    const float* Wg5 = Wgcn + (size_t)L5 * HID * HID;

    if (b < 512) {
        // edges: AGG/CNT pre-zeroed by the stream-ordered memset
        int e = b * 256 + t;                       // 512*256 == E_MAX exactly
        int s = ei[e];
        int d = ei[E_MAX + e];
        if (s < N_SURF && d >= N_SURF) {           // surface -> ligand edges only
            int li = d - N_SURF;
            atomicAdd(&ws[WS_AGG + li * 3 + 0], spos[s * 3 + 0]);
            atomicAdd(&ws[WS_AGG + li * 3 + 1], spos[s * 3 + 1]);
            atomicAdd(&ws[WS_AGG + li * 3 + 2], spos[s * 3 + 2]);
            atomicAdd(&ws[WS_CNT + li], 1.0f);
        }
        // Wp rows: blocks 0..127, wave w -> row b*4+w
        if (b < 128) {
            int row = b * 4 + w;
            const float* Wr = Wg5 + (size_t)row * HID;
            float a0 = 0.f, a1 = 0.f, a2 = 0.f;
            for (int j = lane; j < HID; j += 64) { // coalesced row read
                float v = Wr[j];
                a0 += v * Wpos[j * 3 + 0];
                a1 += v * Wpos[j * 3 + 1];
                a2 += v * Wpos[j * 3 + 2];
            }
            for (int m = 32; m; m >>= 1) {
                a0 += __shfl_xor(a0, m);
                a1 += __shfl_xor(a1, m);
                a2 += __shfl_xor(a2, m);
            }
            if (lane == 0) {
                ws[WS_WP + row * 3 + 0] = a0;
                ws[WS_WP + row * 3 + 1] = a1;
                ws[WS_WP + row * 3 + 2] = a2;
            }
        }
        return;
    }

    int fb = b - 512;                              // 0..68
    if (fb == 68) {                                // bpout: 3 wave-dots
        if (w < 3) {
            float acc = 0.f;
            for (int j = lane; j < HID; j += 64)
                acc += bgcn[L5 * HID + j] * Wpos[j * 3 + w];
            for (int m = 32; m; m >>= 1) acc += __shfl_xor(acc, m);
            if (lane == 0) ws[WS_BPOUT + w] = acc + bpos[w];
        }
        return;
    }

    // direct fold: row R (512) -> out[3] = (R@Wgcn5)@Wpos
    const float* R;
    float* dst;
    if (fb < 64)      { R = Whb   + (size_t)fb * HID;        dst = ws + WS_WHBP + fb * 3; }
    else if (fb < 67) { R = Wsurf + (size_t)(fb - 64) * HID; dst = ws + WS_A3 + (fb - 64) * 3; }
    else              { R = bsurf;                           dst = ws + WS_BSP; }

    float acc0 = 0.f, acc1 = 0.f;                  // cols t and t+256
    #pragma unroll 8
    for (int k = 0; k < HID; ++k) {
        float s = R[k];                            // uniform -> scalar load
        acc0 += s * Wg5[k * HID + t];
        acc1 += s * Wg5[k * HID + t + 256];
    }
    float p0 = acc0 * Wpos[t * 3 + 0] + acc1 * Wpos[(t + 256) * 3 + 0];
    float p1 = acc0 * Wpos[t * 3 + 1] + acc1 * Wpos[(t + 256) * 3 + 1];
    float p2 = acc0 * Wpos[t * 3 + 2] + acc1 * Wpos[(t + 256) * 3 + 2];
    for (int m = 32; m; m >>= 1) {
        p0 += __shfl_xor(p0, m);
        p1 += __shfl_xor(p1, m);
        p2 += __shfl_xor(p2, m);
    }
    __shared__ float s_part[4][3];
    if (lane == 0) { s_part[w][0] = p0; s_part[w][1] = p1; s_part[w][2] = p2; }
    __syncthreads();
    if (t < 3)
        dst[t] = s_part[0][t] + s_part[1][t] + s_part[2][t] + s_part[3][t];
}

// ---- K2: per-ligand pipeline, 2 nodes per block (512 blocks, 2 blk/CU) ----
__global__ __launch_bounds__(256) void k2(
    const float* __restrict__ lpos,  const float* __restrict__ tarr,
    const float* __restrict__ Wt1,   const float* __restrict__ bt1,
    const float* __restrict__ Wt2,   const float* __restrict__ bt2,
    const float* __restrict__ Wlig,  const float* __restrict__ blig,
    const float* __restrict__ Wgate, const float* __restrict__ bgate,
    const float* __restrict__ ws,    float* __restrict__ out)
{
    __shared__ float s_emb[2][64];
    __shared__ float s_h1[2][256];
    __shared__ float s_red[2][2][64];      // [k-half][node][col]
    __shared__ float s_ht[2][64];
    __shared__ float s_out[4][2][3];       // [wave][node][3]
    int t    = threadIdx.x;
    int lane = t & 63;
    int w    = t >> 6;
    int b    = blockIdx.x;
    int i0   = b * 2;

    // emb: waves 0,1 -> node w
    if (w < 2) {
        float tt = tarr[i0 + w];
        const float coef = -0.29710775f;   // -ln(10000)/31
        float ang = tt * expf(coef * (float)(lane & 31));
        s_emb[w][lane] = (lane < 32) ? sinf(ang) : cosf(ang);
    }
    __syncthreads();
    // h1 = gelu(emb @ Wt1 + bt1): thread t owns column t for both nodes
    {
        float bb = bt1[t];
        float acc0 = bb, acc1 = bb;
        #pragma unroll 16
        for (int k = 0; k < 64; ++k) {
            float wv = Wt1[k * 256 + t];
            acc0 += s_emb[0][k] * wv;
            acc1 += s_emb[1][k] * wv;
        }
        s_h1[0][t] = 0.5f * acc0 * (1.f + erff(acc0 * 0.70710678f));
        s_h1[1][t] = 0.5f * acc1 * (1.f + erff(acc1 * 0.70710678f));
    }
    __syncthreads();
    // ht partials: wave w -> node (w&1), k-half (w>>1)*128
    {
        int n  = w & 1;
        int k0 = (w >> 1) * 128;
        float a0 = 0.f, a1 = 0.f, a2 = 0.f, a3 = 0.f;
        #pragma unroll 16
        for (int kk = 0; kk < 128; kk += 4) {
            int k = k0 + kk;
            a0 += s_h1[n][k + 0] * Wt2[(k + 0) * 64 + lane];
            a1 += s_h1[n][k + 1] * Wt2[(k + 1) * 64 + lane];
            a2 += s_h1[n][k + 2] * Wt2[(k + 2) * 64 + lane];
            a3 += s_h1[n][k + 3] * Wt2[(k + 3) * 64 + lane];
        }
        s_red[w >> 1][n][lane] = (a0 + a1) + (a2 + a3);
    }
    __syncthreads();
    if (t < 128) {
        int n = t >> 6;
        s_ht[n][lane] = bt2[lane] + s_red[0][n][lane] + s_red[1][n][lane];
    }
    __syncthreads();

    float px[2], py[2], pz[2];
    #pragma unroll
    for (int n = 0; n < 2; ++n) {
        px[n] = lpos[(i0 + n) * 3 + 0];
        py[n] = lpos[(i0 + n) * 3 + 1];
        pz[n] = lpos[(i0 + n) * 3 + 2];
    }
    float a[2][3] = {};
    // gate + Wp-fold: thread t owns cols t, t+256 (hbias folded via Whbp)
    #pragma unroll
    for (int r = 0; r < 2; ++r) {
        int j = r * 256 + t;
        float bg = bgate[j];
        float g0 = bg, g1 = bg;
        #pragma unroll 16
        for (int k = 0; k < 64; ++k) {
            float wg = Wgate[k * 512 + j];
            g0 += s_ht[0][k] * wg;
            g1 += s_ht[1][k] * wg;
        }
        float wl0 = Wlig[j], wl1 = Wlig[512 + j], wl2 = Wlig[1024 + j], bl = blig[j];
        float wp0 = ws[WS_WP + j * 3 + 0];
        float wp1 = ws[WS_WP + j * 3 + 1];
        float wp2 = ws[WS_WP + j * 3 + 2];
        float g[2] = {g0, g1};
        #pragma unroll
        for (int n = 0; n < 2; ++n) {
            float p  = bl + px[n] * wl0 + py[n] * wl1 + pz[n] * wl2;
            float hl = p * (1.f / (1.f + expf(-g[n])));
            a[n][0] += hl * wp0;
            a[n][1] += hl * wp1;
            a[n][2] += hl * wp2;
        }
    }
    // + h_time @ Whbp (64x3 precomputed)
    if (t < 64) {
        float h0  = ws[WS_WHBP + t * 3 + 0];
        float h1v = ws[WS_WHBP + t * 3 + 1];
        float h2  = ws[WS_WHBP + t * 3 + 2];
        #pragma unroll
        for (int n = 0; n < 2; ++n) {
            float ht = s_ht[n][t];
            a[n][0] += ht * h0;
            a[n][1] += ht * h1v;
            a[n][2] += ht * h2;
        }
    }
    #pragma unroll
    for (int n = 0; n < 2; ++n)
        #pragma unroll
        for (int jp = 0; jp < 3; ++jp)
            for (int m = 32; m; m >>= 1) a[n][jp] += __shfl_xor(a[n][jp], m);
    if (lane == 0)
        #pragma unroll
        for (int n = 0; n < 2; ++n)
            #pragma unroll
            for (int jp = 0; jp < 3; ++jp) s_out[w][n][jp] = a[n][jp];
    __syncthreads();
    if (t < 2) {   // thread t -> node i0+t epilogue
        int n = t, i = i0 + n;
        float d  = ws[WS_CNT + i];
        float s1 = 1.f / sqrtf(1.f + d);
        float s2 = 1.f / (1.f + d);
        float c  = s1 * d;
        float ax = s1 * ws[WS_AGG + i * 3 + 0];
        float ay = s1 * ws[WS_AGG + i * 3 + 1];
        float az = s1 * ws[WS_AGG + i * 3 + 2];
        #pragma unroll
        for (int jp = 0; jp < 3; ++jp) {
            float bb = s_out[0][n][jp] + s_out[1][n][jp] + s_out[2][n][jp] + s_out[3][n][jp];
            out[i * 3 + jp] = ax * ws[WS_A3 + 0 + jp] +
                              ay * ws[WS_A3 + 3 + jp] +
                              az * ws[WS_A3 + 6 + jp] +
                              c  * ws[WS_BSP + jp]    +
                              s2 * bb                 +
                              ws[WS_BPOUT + jp];
        }
    }
}

extern "C" void kernel_launch(void* const* d_in, const int* in_sizes, int n_in,
                              void* d_out, int out_size, void* d_ws, size_t ws_size,
                              hipStream_t stream) {
    const float* spos  = (const float*)d_in[0];
    const float* lpos  = (const float*)d_in[1];
    const float* tarr  = (const float*)d_in[2];
    const int*   ei    = (const int*)  d_in[3];
    const float* Wsurf = (const float*)d_in[6];
    const float* bsurf = (const float*)d_in[7];
    const float* Wt1   = (const float*)d_in[8];
    const float* bt1   = (const float*)d_in[9];
    const float* Wt2   = (const float*)d_in[10];
    const float* bt2   = (const float*)d_in[11];
    const float* Wlig  = (const float*)d_in[12];
    const float* blig  = (const float*)d_in[13];
    const float* Wgate = (const float*)d_in[14];
    const float* bgate = (const float*)d_in[15];
    const float* Whb   = (const float*)d_in[16];
    const float* Wgcn  = (const float*)d_in[17];
    const float* bgcn  = (const float*)d_in[18];
    const float* Wpos  = (const float*)d_in[19];
    const float* bpos  = (const float*)d_in[20];
    float* ws  = (float*)d_ws;
    float* out = (float*)d_out;

    // zero AGG/CNT (stream-ordered; provides the zero->atomics dependency)
    hipMemsetAsync((char*)d_ws + WS_ZERO_BEGIN * sizeof(float), 0,
                   WS_ZERO_COUNT * sizeof(float), stream);

    hipLaunchKernelGGL(k1, dim3(581), dim3(256), 0, stream,
                       Wgcn, Wpos, Wsurf, bsurf, bgcn, bpos, Whb, ei, spos, ws);
    hipLaunchKernelGGL(k2, dim3(N_LIG / 2), dim3(256), 0, stream,
                       lpos, tarr, Wt1, bt1, Wt2, bt2,
                       Wlig, blig, Wgate, bgate, ws, out);
}